// Round 1
// baseline (189.717 us; speedup 1.0000x reference)
//
#include <hip/hip_runtime.h>

// sigmoid( (Z[src] . Z[dst]) * w + b ) per edge.
// 16 lanes per edge: lane i loads float4 at row float4-offset i and i+16
// (two fully-coalesced 256B segments per 16-lane group), 8 MACs/lane,
// then 4-step shfl_xor reduce within the 16-lane group.
__global__ __launch_bounds__(256) void edge_sigmoid_dot(
    const float* __restrict__ Z,
    const int*   __restrict__ ei,   // [2*E] row-major: src=[0,E), dst=[E,2E)
    const float* __restrict__ w,    // [1]
    const float* __restrict__ b,    // [1]
    float*       __restrict__ out,  // [E]
    int E)
{
    int tid  = blockIdx.x * blockDim.x + threadIdx.x;
    int edge = tid >> 4;
    int lane = tid & 15;
    if (edge >= E) return;

    int s = ei[edge];
    int d = ei[edge + E];

    const float4* zs = reinterpret_cast<const float4*>(Z) + (size_t)s * 32 + lane;
    const float4* zd = reinterpret_cast<const float4*>(Z) + (size_t)d * 32 + lane;

    float4 a0 = zs[0];
    float4 a1 = zs[16];
    float4 c0 = zd[0];
    float4 c1 = zd[16];

    float p = a0.x*c0.x + a0.y*c0.y + a0.z*c0.z + a0.w*c0.w
            + a1.x*c1.x + a1.y*c1.y + a1.z*c1.z + a1.w*c1.w;

    // reduce across the 16-lane group
    p += __shfl_xor(p, 1, 16);
    p += __shfl_xor(p, 2, 16);
    p += __shfl_xor(p, 4, 16);
    p += __shfl_xor(p, 8, 16);

    if (lane == 0) {
        float x = p * w[0] + b[0];
        out[edge] = 1.0f / (1.0f + expf(-x));
    }
}

extern "C" void kernel_launch(void* const* d_in, const int* in_sizes, int n_in,
                              void* d_out, int out_size, void* d_ws, size_t ws_size,
                              hipStream_t stream) {
    const float* Z  = (const float*)d_in[0];
    const int*   ei = (const int*)d_in[1];
    const float* w  = (const float*)d_in[2];
    const float* b  = (const float*)d_in[3];
    float* out = (float*)d_out;

    int E = in_sizes[1] / 2;  // edge_index is (2, E)

    const int block = 256;
    long long total_threads = (long long)E * 16;
    int grid = (int)((total_threads + block - 1) / block);

    edge_sigmoid_dot<<<grid, block, 0, stream>>>(Z, ei, w, b, out, E);
}

// Round 2
// 187.123 us; speedup vs baseline: 1.0139x; 1.0139x over previous
//
#include <hip/hip_runtime.h>

// sigmoid( (Z[src] . Z[dst]) * w + b ) per edge.
// 16 lanes per edge-PAIR group: each group handles 2 edges; all index loads
// and all 8 gather dwordx4 loads are issued before any arithmetic, doubling
// memory-level parallelism per wave vs the 1-edge version.
__global__ __launch_bounds__(256) void edge_sigmoid_dot2(
    const float* __restrict__ Z,
    const int*   __restrict__ ei,   // [2*E] row-major: src=[0,E), dst=[E,2E)
    const float* __restrict__ w,    // [1]
    const float* __restrict__ b,    // [1]
    float*       __restrict__ out,  // [E]
    int E)
{
    int tid  = blockIdx.x * blockDim.x + threadIdx.x;
    int grp  = tid >> 4;          // group of 16 lanes -> 2 edges
    int lane = tid & 15;
    int e0 = grp * 2;
    if (e0 >= E) return;
    bool has2 = (e0 + 1) < E;

    // Uniform (per-group) index loads, both streams, both edges.
    int2 sp = *reinterpret_cast<const int2*>(&ei[e0]);
    int2 dp = *reinterpret_cast<const int2*>(&ei[e0 + E]);
    int s1 = has2 ? sp.y : sp.x;
    int d1 = has2 ? dp.y : dp.x;

    const float4* Z4 = reinterpret_cast<const float4*>(Z);
    const float4* as0 = Z4 + (size_t)sp.x * 32 + lane;
    const float4* ad0 = Z4 + (size_t)dp.x * 32 + lane;
    const float4* as1 = Z4 + (size_t)s1   * 32 + lane;
    const float4* ad1 = Z4 + (size_t)d1   * 32 + lane;

    // Issue all 8 gather loads back-to-back (8 x 16B per lane in flight).
    float4 a00 = as0[0];
    float4 a01 = as0[16];
    float4 c00 = ad0[0];
    float4 c01 = ad0[16];
    float4 a10 = as1[0];
    float4 a11 = as1[16];
    float4 c10 = ad1[0];
    float4 c11 = ad1[16];

    float p0 = a00.x*c00.x + a00.y*c00.y + a00.z*c00.z + a00.w*c00.w
             + a01.x*c01.x + a01.y*c01.y + a01.z*c01.z + a01.w*c01.w;
    float p1 = a10.x*c10.x + a10.y*c10.y + a10.z*c10.z + a10.w*c10.w
             + a11.x*c11.x + a11.y*c11.y + a11.z*c11.z + a11.w*c11.w;

    // reduce both dots across the 16-lane group
    p0 += __shfl_xor(p0, 1, 16);  p1 += __shfl_xor(p1, 1, 16);
    p0 += __shfl_xor(p0, 2, 16);  p1 += __shfl_xor(p1, 2, 16);
    p0 += __shfl_xor(p0, 4, 16);  p1 += __shfl_xor(p1, 4, 16);
    p0 += __shfl_xor(p0, 8, 16);  p1 += __shfl_xor(p1, 8, 16);

    if (lane == 0) {
        float ww = w[0], bb = b[0];
        float y0 = 1.0f / (1.0f + expf(-(p0 * ww + bb)));
        if (has2) {
            float y1 = 1.0f / (1.0f + expf(-(p1 * ww + bb)));
            float2 y = make_float2(y0, y1);
            *reinterpret_cast<float2*>(&out[e0]) = y;   // e0 even -> 8B aligned
        } else {
            out[e0] = y0;
        }
    }
}

extern "C" void kernel_launch(void* const* d_in, const int* in_sizes, int n_in,
                              void* d_out, int out_size, void* d_ws, size_t ws_size,
                              hipStream_t stream) {
    const float* Z  = (const float*)d_in[0];
    const int*   ei = (const int*)d_in[1];
    const float* w  = (const float*)d_in[2];
    const float* b  = (const float*)d_in[3];
    float* out = (float*)d_out;

    int E = in_sizes[1] / 2;  // edge_index is (2, E)

    const int block = 256;
    long long groups = (E + 1) / 2;                 // 2 edges per 16-lane group
    long long total_threads = groups * 16;
    int grid = (int)((total_threads + block - 1) / block);

    edge_sigmoid_dot2<<<grid, block, 0, stream>>>(Z, ei, w, b, out, E);
}

// Round 3
// 91.474 us; speedup vs baseline: 2.0740x; 2.0457x over previous
//
#include <hip/hip_runtime.h>

typedef _Float16 half2_t __attribute__((ext_vector_type(2)));

union H8 {
    uint4   u;
    half2_t h2[4];
    _Float16 h[8];
};

// Pass 1: convert Z (fp32, N*D elems) to fp16 rows in workspace.
// Each thread converts 8 consecutive floats -> one 16B uint4 of 8 halves.
__global__ __launch_bounds__(256) void convert_f32_to_f16(
    const float* __restrict__ Z, uint4* __restrict__ Zh, int nv4)
{
    int i = blockIdx.x * blockDim.x + threadIdx.x;
    if (i >= nv4) return;
    const float4* Z4 = reinterpret_cast<const float4*>(Z);
    float4 a = Z4[(size_t)i * 2];
    float4 b = Z4[(size_t)i * 2 + 1];
    H8 o;
    o.h[0] = (_Float16)a.x; o.h[1] = (_Float16)a.y;
    o.h[2] = (_Float16)a.z; o.h[3] = (_Float16)a.w;
    o.h[4] = (_Float16)b.x; o.h[5] = (_Float16)b.y;
    o.h[6] = (_Float16)b.z; o.h[7] = (_Float16)b.w;
    Zh[i] = o.u;
}

// Pass 2: sigmoid( (Zh[src] . Zh[dst]) * w + b ) per edge.
// fp16 rows are 256B: 16 lanes x 16B = one row per instruction per group.
// 2 edges per 16-lane group; fp32 accumulation via v_dot2_f32_f16.
__global__ __launch_bounds__(256) void edge_sigmoid_dot_h(
    const uint4* __restrict__ Zh,
    const int*   __restrict__ ei,   // [2*E]: src=[0,E), dst=[E,2E)
    const float* __restrict__ w,
    const float* __restrict__ b,
    float*       __restrict__ out,
    int E)
{
    int tid  = blockIdx.x * blockDim.x + threadIdx.x;
    int grp  = tid >> 4;
    int lane = tid & 15;
    int e0 = grp * 2;
    if (e0 >= E) return;
    bool has2 = (e0 + 1) < E;

    int2 sp = *reinterpret_cast<const int2*>(&ei[e0]);
    int2 dp = *reinterpret_cast<const int2*>(&ei[e0 + E]);
    int s1 = has2 ? sp.y : sp.x;
    int d1 = has2 ? dp.y : dp.x;

    // Issue all 4 row loads (16B/lane each) before any arithmetic.
    H8 a0, c0, a1, c1;
    a0.u = Zh[(size_t)sp.x * 16 + lane];
    c0.u = Zh[(size_t)dp.x * 16 + lane];
    a1.u = Zh[(size_t)s1   * 16 + lane];
    c1.u = Zh[(size_t)d1   * 16 + lane];

    float p0 = 0.0f, p1 = 0.0f;
#if __has_builtin(__builtin_amdgcn_fdot2)
#pragma unroll
    for (int k = 0; k < 4; ++k) {
        p0 = __builtin_amdgcn_fdot2(a0.h2[k], c0.h2[k], p0, false);
        p1 = __builtin_amdgcn_fdot2(a1.h2[k], c1.h2[k], p1, false);
    }
#else
#pragma unroll
    for (int k = 0; k < 8; ++k) {
        p0 += (float)a0.h[k] * (float)c0.h[k];
        p1 += (float)a1.h[k] * (float)c1.h[k];
    }
#endif

    p0 += __shfl_xor(p0, 1, 16);  p1 += __shfl_xor(p1, 1, 16);
    p0 += __shfl_xor(p0, 2, 16);  p1 += __shfl_xor(p1, 2, 16);
    p0 += __shfl_xor(p0, 4, 16);  p1 += __shfl_xor(p1, 4, 16);
    p0 += __shfl_xor(p0, 8, 16);  p1 += __shfl_xor(p1, 8, 16);

    if (lane == 0) {
        float ww = w[0], bb = b[0];
        float y0 = 1.0f / (1.0f + expf(-(p0 * ww + bb)));
        if (has2) {
            float y1 = 1.0f / (1.0f + expf(-(p1 * ww + bb)));
            *reinterpret_cast<float2*>(&out[e0]) = make_float2(y0, y1);
        } else {
            out[e0] = y0;
        }
    }
}

// fp32 fallback (identical to R2 kernel) if workspace is too small.
__global__ __launch_bounds__(256) void edge_sigmoid_dot2(
    const float* __restrict__ Z,
    const int*   __restrict__ ei,
    const float* __restrict__ w,
    const float* __restrict__ b,
    float*       __restrict__ out,
    int E)
{
    int tid  = blockIdx.x * blockDim.x + threadIdx.x;
    int grp  = tid >> 4;
    int lane = tid & 15;
    int e0 = grp * 2;
    if (e0 >= E) return;
    bool has2 = (e0 + 1) < E;

    int2 sp = *reinterpret_cast<const int2*>(&ei[e0]);
    int2 dp = *reinterpret_cast<const int2*>(&ei[e0 + E]);
    int s1 = has2 ? sp.y : sp.x;
    int d1 = has2 ? dp.y : dp.x;

    const float4* Z4 = reinterpret_cast<const float4*>(Z);
    const float4* as0 = Z4 + (size_t)sp.x * 32 + lane;
    const float4* ad0 = Z4 + (size_t)dp.x * 32 + lane;
    const float4* as1 = Z4 + (size_t)s1   * 32 + lane;
    const float4* ad1 = Z4 + (size_t)d1   * 32 + lane;

    float4 a00 = as0[0]; float4 a01 = as0[16];
    float4 c00 = ad0[0]; float4 c01 = ad0[16];
    float4 a10 = as1[0]; float4 a11 = as1[16];
    float4 c10 = ad1[0]; float4 c11 = ad1[16];

    float p0 = a00.x*c00.x + a00.y*c00.y + a00.z*c00.z + a00.w*c00.w
             + a01.x*c01.x + a01.y*c01.y + a01.z*c01.z + a01.w*c01.w;
    float p1 = a10.x*c10.x + a10.y*c10.y + a10.z*c10.z + a10.w*c10.w
             + a11.x*c11.x + a11.y*c11.y + a11.z*c11.z + a11.w*c11.w;

    p0 += __shfl_xor(p0, 1, 16);  p1 += __shfl_xor(p1, 1, 16);
    p0 += __shfl_xor(p0, 2, 16);  p1 += __shfl_xor(p1, 2, 16);
    p0 += __shfl_xor(p0, 4, 16);  p1 += __shfl_xor(p1, 4, 16);
    p0 += __shfl_xor(p0, 8, 16);  p1 += __shfl_xor(p1, 8, 16);

    if (lane == 0) {
        float ww = w[0], bb = b[0];
        float y0 = 1.0f / (1.0f + expf(-(p0 * ww + bb)));
        if (has2) {
            float y1 = 1.0f / (1.0f + expf(-(p1 * ww + bb)));
            *reinterpret_cast<float2*>(&out[e0]) = make_float2(y0, y1);
        } else {
            out[e0] = y0;
        }
    }
}

extern "C" void kernel_launch(void* const* d_in, const int* in_sizes, int n_in,
                              void* d_out, int out_size, void* d_ws, size_t ws_size,
                              hipStream_t stream) {
    const float* Z  = (const float*)d_in[0];
    const int*   ei = (const int*)d_in[1];
    const float* w  = (const float*)d_in[2];
    const float* b  = (const float*)d_in[3];
    float* out = (float*)d_out;

    int nz = in_sizes[0];          // N*D
    int E  = in_sizes[1] / 2;      // edge_index is (2, E)

    const int block = 256;
    long long groups = (E + 1) / 2;
    int grid_e = (int)((groups * 16 + block - 1) / block);

    size_t need = (size_t)nz * sizeof(_Float16);
    if (ws_size >= need) {
        uint4* Zh = (uint4*)d_ws;
        int nv4 = nz / 8;
        int grid_c = (nv4 + block - 1) / block;
        convert_f32_to_f16<<<grid_c, block, 0, stream>>>(Z, Zh, nv4);
        edge_sigmoid_dot_h<<<grid_e, block, 0, stream>>>(Zh, ei, w, b, out, E);
    } else {
        edge_sigmoid_dot2<<<grid_e, block, 0, stream>>>(Z, ei, w, b, out, E);
    }
}